// Round 1
// 424.465 us; speedup vs baseline: 1.0603x; 1.0603x over previous
//
#include <hip/hip_runtime.h>
#include <math.h>

#define DIM 768
#define HEADS 12
#define DH 64
#define NSEQ 4096
#define BATCH 2
#define BH (BATCH * HEADS)

typedef __attribute__((ext_vector_type(8))) short bf16x8;
typedef __attribute__((ext_vector_type(4))) float f32x4;

typedef const __attribute__((address_space(1))) unsigned char* as1_u8;
typedef __attribute__((address_space(3))) unsigned char* as3_u8;

// round-half-up bf16: <=0.5 ULP, 2 VALU ops
__device__ __forceinline__ unsigned short f2bf(float x) {
  return (unsigned short)((__float_as_uint(x) + 0x8000u) >> 16);
}

// raw v_exp_f32 = 2^x. s_nop 0 covers the trans->VALU 1-wait-state hazard.
__device__ __forceinline__ float exp2_fast(float x) {
  float r;
  asm volatile("v_exp_f32 %0, %1\n\ts_nop 0" : "=v"(r) : "v"(x));
  return r;
}

// async global->LDS DMA, 16B per lane; LDS dest = wave-uniform base + lane*16
__device__ __forceinline__ void gl16(const void* g, void* l) {
  __builtin_amdgcn_global_load_lds((as1_u8)g, (as3_u8)l, 16, 0, 0);
}

// ---------------------------------------------------------------------------
// fp32 -> bf16 elementwise (x). 8 elems/thread.
// ---------------------------------------------------------------------------
__global__ __launch_bounds__(256) void cvt_bf16(const float* __restrict__ in,
                                                unsigned short* __restrict__ out,
                                                int n) {
  int i = (blockIdx.x * 256 + threadIdx.x) * 8;
  if (i >= n) return;
  float4 a = *(const float4*)(in + i);
  float4 b = *(const float4*)(in + i + 4);
  ushort4 v0, v1;
  v0.x = f2bf(a.x); v0.y = f2bf(a.y); v0.z = f2bf(a.z); v0.w = f2bf(a.w);
  v1.x = f2bf(b.x); v1.y = f2bf(b.y); v1.z = f2bf(b.z); v1.w = f2bf(b.w);
  *(ushort4*)(out + i) = v0;
  *(ushort4*)(out + i + 4) = v1;
}

// ---------------------------------------------------------------------------
// Transpose + convert: in [K][N] fp32 -> out [N][K] bf16. 32x32 tiles.
// ---------------------------------------------------------------------------
__global__ __launch_bounds__(256) void transpose_cvt(const float* __restrict__ in,
                                                     unsigned short* __restrict__ out,
                                                     int K, int N) {
  __shared__ unsigned short s[32][34];
  int t = threadIdx.x;
  int tx = t & 31, ty = t >> 5;
  int n0 = blockIdx.x * 32, k0 = blockIdx.y * 32;
#pragma unroll
  for (int i = 0; i < 4; ++i) {
    int r = ty + i * 8;
    s[r][tx] = f2bf(in[(size_t)(k0 + r) * N + n0 + tx]);
  }
  __syncthreads();
#pragma unroll
  for (int i = 0; i < 4; ++i) {
    int r = ty + i * 8;
    out[(size_t)(n0 + r) * K + k0 + tx] = s[tx][r];
  }
}

// ---------------------------------------------------------------------------
// V [bh][n][64] -> Vt [bh][64][n], bf16, 64x64 LDS tiles.
// ---------------------------------------------------------------------------
__global__ __launch_bounds__(256) void vtrans(const unsigned short* __restrict__ Vb,
                                              unsigned short* __restrict__ Vt) {
  __shared__ unsigned short s[64][72];
  int t = threadIdx.x;
  int bh = blockIdx.y;
  int n0 = blockIdx.x * 64;
  const unsigned short* src = Vb + ((size_t)bh * NSEQ + n0) * DH;
#pragma unroll
  for (int i = 0; i < 2; ++i) {
    int idx = t + i * 256;
    int row = idx >> 3, ch = (idx & 7) * 8;
    *(uint4*)&s[row][ch] = *(const uint4*)(src + (size_t)row * DH + ch);
  }
  __syncthreads();
  unsigned short* dst = Vt + (size_t)bh * DH * NSEQ + n0;
#pragma unroll
  for (int i = 0; i < 2; ++i) {
    int idx = t + i * 256;
    int dh = idx >> 3, ch = (idx & 7) * 8;
    unsigned short tmp[8];
#pragma unroll
    for (int j = 0; j < 8; ++j) tmp[j] = s[ch + j][dh];
    *(uint4*)&dst[(size_t)dh * NSEQ + ch] = *(uint4*)tmp;
  }
}

// ---------------------------------------------------------------------------
// bf16 MFMA GEMM: C[M,N] = A[M,K] @ Bt[N,K]^T + bias.
// TM x 128 tile, BK=64, 256 thr (4 waves, 2x2), register staging, prefetch
// pipeline. mode 0 (QKV): vectorized epilogue via LDS round-trip (full-line
// 32 B/lane stores) -> Qb (scaled)/Kb/V0 all [bh][n][64] bf16.
// mode 1: fp32 row-major out.
// ---------------------------------------------------------------------------
template <int TM>
__global__ __launch_bounds__(256) void gemm_bt(
    const unsigned short* __restrict__ A, const unsigned short* __restrict__ Bt,
    const float* __restrict__ bias, float* __restrict__ outf,
    unsigned short* __restrict__ Qb, unsigned short* __restrict__ Kb,
    unsigned short* __restrict__ V0, int M, int N, int K, int mode) {
  __shared__ unsigned short As[TM * 72];
  __shared__ unsigned short Bs[128 * 72];  // also reused as fp32 C-scratch in epilogue
  constexpr int MI = TM / 32;
  const int t = threadIdx.x;
  const int wave = t >> 6, lane = t & 63;
  const int ln16 = lane & 15, quad = lane >> 4;
  const int rb = blockIdx.y, cb = blockIdx.x;
  const int rw = (wave >> 1) * (TM / 2);
  const int cw = (wave & 1) * 64;

  const int srow = lane >> 3;       // 0..7
  const int scol = (lane & 7) * 8;  // 16B chunks

  const unsigned short* gA = A + (size_t)(rb * TM + wave * (TM / 4) + srow) * K + scol;
  const unsigned short* gB = Bt + (size_t)(cb * 128 + wave * 32 + srow) * K + scol;

  f32x4 acc[MI][4];
#pragma unroll
  for (int i = 0; i < MI; ++i)
#pragma unroll
    for (int j = 0; j < 4; ++j) acc[i][j] = (f32x4){0.f, 0.f, 0.f, 0.f};

  uint4 av[MI], bv[4];
#pragma unroll
  for (int i = 0; i < MI; ++i) av[i] = *(const uint4*)(gA + (size_t)i * 8 * K);
#pragma unroll
  for (int i = 0; i < 4; ++i) bv[i] = *(const uint4*)(gB + (size_t)i * 8 * K);

  for (int k0 = 0; k0 < K; k0 += 64) {
    __syncthreads();  // previous tile fully consumed
#pragma unroll
    for (int i = 0; i < MI; ++i)
      *(uint4*)&As[(wave * (TM / 4) + i * 8 + srow) * 72 + scol] = av[i];
#pragma unroll
    for (int i = 0; i < 4; ++i)
      *(uint4*)&Bs[(wave * 32 + i * 8 + srow) * 72 + scol] = bv[i];
    __syncthreads();
    if (k0 + 64 < K) {  // prefetch next tile; compute below covers latency
#pragma unroll
      for (int i = 0; i < MI; ++i)
        av[i] = *(const uint4*)(gA + (size_t)i * 8 * K + k0 + 64);
#pragma unroll
      for (int i = 0; i < 4; ++i)
        bv[i] = *(const uint4*)(gB + (size_t)i * 8 * K + k0 + 64);
    }
#pragma unroll
    for (int kh = 0; kh < 2; ++kh) {
      bf16x8 a[MI], b[4];
#pragma unroll
      for (int mi = 0; mi < MI; ++mi)
        a[mi] = *(const bf16x8*)&As[(rw + mi * 16 + ln16) * 72 + kh * 32 + quad * 8];
#pragma unroll
      for (int ni = 0; ni < 4; ++ni)
        b[ni] = *(const bf16x8*)&Bs[(cw + ni * 16 + ln16) * 72 + kh * 32 + quad * 8];
#pragma unroll
      for (int mi = 0; mi < MI; ++mi)
#pragma unroll
        for (int ni = 0; ni < 4; ++ni)
          acc[mi][ni] = __builtin_amdgcn_mfma_f32_16x16x32_bf16(a[mi], b[ni],
                                                                acc[mi][ni], 0, 0, 0);
    }
  }

  if (mode == 0) {
    __syncthreads();  // all waves done reading Bs; reuse as fp32 C-scratch
    // 768^-0.5 * log2(e): attention uses raw v_exp_f32 (2^x), so the log2e
    // factor is folded into the Q scale here. exp2(S*log2e) == exp(S).
    const float scale = 0.0520587731f;
    int col0abs = cb * 128 + cw;                 // multiple of 64
    int which = (col0abs >= 2 * DIM) ? 2 : ((col0abs >= DIM) ? 1 : 0);
    int h = (col0abs - which * DIM) >> 6;        // wave covers one full head
    unsigned short* dstp = (which == 0) ? Qb : ((which == 1) ? Kb : V0);
    const float mul = (which == 0) ? scale : 1.f;
    float* Cs = (float*)Bs + wave * (16 * 68);   // 16 rows x 68 floats per wave
    float bvv[4];
#pragma unroll
    for (int ni = 0; ni < 4; ++ni) bvv[ni] = bias[col0abs + ni * 16 + ln16];
#pragma unroll
    for (int mi = 0; mi < MI; ++mi) {
#pragma unroll
      for (int ni = 0; ni < 4; ++ni)
#pragma unroll
        for (int r = 0; r < 4; ++r)
          Cs[(quad * 4 + r) * 68 + ni * 16 + ln16] = (acc[mi][ni][r] + bvv[ni]) * mul;
      __asm__ volatile("s_waitcnt lgkmcnt(0)" ::: "memory");  // wave-local region
      int token = rb * TM + rw + mi * 16 + ln16;
      int bb = token >> 12, nn = token & (NSEQ - 1);
      const float* src = &Cs[ln16 * 68 + quad * 16];
      float4 c0 = *(const float4*)(src + 0);
      float4 c1 = *(const float4*)(src + 4);
      float4 c2 = *(const float4*)(src + 8);
      float4 c3 = *(const float4*)(src + 12);
      unsigned short tmp[16];
      tmp[0] = f2bf(c0.x);  tmp[1] = f2bf(c0.y);  tmp[2] = f2bf(c0.z);  tmp[3] = f2bf(c0.w);
      tmp[4] = f2bf(c1.x);  tmp[5] = f2bf(c1.y);  tmp[6] = f2bf(c1.z);  tmp[7] = f2bf(c1.w);
      tmp[8] = f2bf(c2.x);  tmp[9] = f2bf(c2.y);  tmp[10] = f2bf(c2.z); tmp[11] = f2bf(c2.w);
      tmp[12] = f2bf(c3.x); tmp[13] = f2bf(c3.y); tmp[14] = f2bf(c3.z); tmp[15] = f2bf(c3.w);
      unsigned short* dp =
          dstp + ((size_t)(bb * HEADS + h) * NSEQ + nn) * DH + quad * 16;
      *(uint4*)&dp[0] = *(uint4*)&tmp[0];
      *(uint4*)&dp[8] = *(uint4*)&tmp[8];
      __asm__ volatile("s_waitcnt lgkmcnt(0)" ::: "memory");  // reads done before next mi writes
    }
  } else {
#pragma unroll
    for (int ni = 0; ni < 4; ++ni) {
      int col = cb * 128 + cw + ni * 16 + ln16;
      float bv2 = bias[col];
#pragma unroll
      for (int mi = 0; mi < MI; ++mi)
#pragma unroll
        for (int r = 0; r < 4; ++r) {
          int token = rb * TM + rw + mi * 16 + quad * 4 + r;
          outf[(size_t)token * N + col] = acc[mi][ni][r] + bv2;
        }
    }
  }
}

// ---------------------------------------------------------------------------
// MFMA flash attention v4. Changes vs v3:
//  * swapped QK^T (mfma(K,Q)): query ends up lane-local (col=ln16) so the
//    P matrix never touches LDS: v_cvt_pk_bf16_f32 packs adjacent-key pairs,
//    then permlane16_swap(permlane32_swap(.)) forms the PV A-fragment
//    entirely in registers (replaces 32 ds_write_u16 + 4 ds_read_b128/tile).
//  * K/V staged via global_load_lds (DMA, no ds_write), double-buffered,
//    ONE barrier per tile; XOR-swizzled content via pre-swizzled global
//    source (rule #21: linear LDS dest + inverse-swz source + swz read).
//  * denominator ones-fragment is a register constant (was Vones LDS).
//  * P = exp2(S) directly (log2e folded into Q scale in gemm epilogue).
// LDS: 32 KB (2 x dbuf x 8 KB), no Ps/Vones.
// ---------------------------------------------------------------------------
__global__ __launch_bounds__(256, 3) void attn_mfma4(
    const unsigned short* __restrict__ Qg, const unsigned short* __restrict__ Kg,
    const unsigned short* __restrict__ Vtg, unsigned short* __restrict__ ctxb) {
  __shared__ unsigned short Ks[2][64][64];   // [buf][key][dh], chunk-XOR-swizzled
  __shared__ unsigned short Vts[2][64][64];  // [buf][dh][key], chunk-XOR-swizzled

  const int t = threadIdx.x;
  const int wave = t >> 6, lane = t & 63;
  const int ln16 = lane & 15, quad = lane >> 4;
  const int bh = blockIdx.y;
  const int q0 = blockIdx.x * 128;

  // Q fragments (registers, whole kernel)
  const unsigned short* Qp = Qg + ((size_t)bh * NSEQ + q0 + wave * 32) * DH;
  bf16x8 qf[2][2];
#pragma unroll
  for (int mi = 0; mi < 2; ++mi)
#pragma unroll
    for (int kh = 0; kh < 2; ++kh)
      qf[mi][kh] = *(const bf16x8*)(Qp + (size_t)(mi * 16 + ln16) * DH + kh * 32 + quad * 8);

  f32x4 O[2][5];
#pragma unroll
  for (int mi = 0; mi < 2; ++mi)
#pragma unroll
    for (int nt = 0; nt < 5; ++nt) O[mi][nt] = (f32x4){0.f, 0.f, 0.f, 0.f};

  const unsigned short* Kbase = Kg + (size_t)bh * NSEQ * DH;
  const unsigned short* Vbase = Vtg + (size_t)bh * DH * NSEQ;

  // staging geometry: per gl16 a wave covers 8 rows x 128B; row = lane>>3,
  // chunk = lane&7. Source chunk pre-swizzled by row&7 so that
  // LDS[row][c] = true[row][c ^ (row&7)] (16B-chunk XOR swizzle).
  const int row8 = lane >> 3;
  const int csw = (lane & 7) ^ row8;

  auto stage = [&](int b, int kk) {
#pragma unroll
    for (int i = 0; i < 2; ++i) {
      int rr = wave * 16 + i * 8;
      gl16(Kbase + (size_t)(kk + rr + row8) * DH + csw * 8, &Ks[b][rr][0]);
      gl16(Vbase + (size_t)(rr + row8) * NSEQ + kk + csw * 8, &Vts[b][rr][0]);
    }
  };

  // ones B-fragment for denominator column (row 0 of B = ones)
  union { unsigned int u[4]; bf16x8 v; } VO;
  {
    unsigned int ow = (ln16 == 0) ? 0x3F803F80u : 0u;
    VO.u[0] = ow; VO.u[1] = ow; VO.u[2] = ow; VO.u[3] = ow;
  }
  const bf16x8 vone = VO.v;

  stage(0, 0);
  const int sw = ln16 & 7;
  int buf = 0;

  for (int k0 = 0; k0 < NSEQ; k0 += 64) {
    asm volatile("s_waitcnt vmcnt(0)" ::: "memory");  // own DMA done
    __syncthreads();                                  // everyone's DMA done; prev tile consumed
    if (k0 + 64 < NSEQ) stage(buf ^ 1, k0 + 64);      // prefetch DMA under this tile's compute

    // S~ = K.Q^T  (swapped operands: col=ln16=query, row=quad*4+r=key)
    f32x4 S[2][4];
    __builtin_amdgcn_s_setprio(1);
#pragma unroll
    for (int nt = 0; nt < 4; ++nt) {
      const unsigned short* kr = &Ks[buf][nt * 16 + ln16][0];
      bf16x8 kb0 = *(const bf16x8*)(kr + (quad ^ sw) * 8);
      bf16x8 kb1 = *(const bf16x8*)(kr + ((quad + 4) ^ sw) * 8);
#pragma unroll
      for (int mi = 0; mi < 2; ++mi) {
        f32x4 s = (f32x4){0.f, 0.f, 0.f, 0.f};
        s = __builtin_amdgcn_mfma_f32_16x16x32_bf16(kb0, qf[mi][0], s, 0, 0, 0);
        s = __builtin_amdgcn_mfma_f32_16x16x32_bf16(kb1, qf[mi][1], s, 0, 0, 0);
        S[mi][nt] = s;
      }
    }
    __builtin_amdgcn_s_setprio(0);

    // P = exp2(S~) -> bf16 pack -> in-register quad exchange -> PV A-frags.
    // Lane (ln16,quad) holds P[q=mi*16+ln16][key=nt*16+quad*4+r].
    // c[nt][u] = pk(key 4q+2u, 4q+2u+1). Target word p of pa[mi][kh] needs
    // key kh*32+8*quad+2p => nt=2kh+(quad>>1), src-quad=2*(quad&1)+(p>>1):
    // (w0,w2) = swap16(swap32(c[2kh][0], c[2kh+1][0])), (w1,w3) likewise u=1.
    bf16x8 pa[2][2];
#pragma unroll
    for (int mi = 0; mi < 2; ++mi) {
      unsigned int c[4][2];
#pragma unroll
      for (int nt = 0; nt < 4; ++nt) {
        float e0 = exp2_fast(S[mi][nt][0]);
        float e1 = exp2_fast(S[mi][nt][1]);
        float e2 = exp2_fast(S[mi][nt][2]);
        float e3 = exp2_fast(S[mi][nt][3]);
        asm volatile("v_cvt_pk_bf16_f32 %0, %1, %2" : "=v"(c[nt][0]) : "v"(e0), "v"(e1));
        asm volatile("v_cvt_pk_bf16_f32 %0, %1, %2" : "=v"(c[nt][1]) : "v"(e2), "v"(e3));
      }
#pragma unroll
      for (int kh = 0; kh < 2; ++kh) {
        unsigned int a0 = c[2 * kh][0], a1 = c[2 * kh][1];
        unsigned int a2 = c[2 * kh + 1][0], a3 = c[2 * kh + 1][1];
        asm volatile("v_permlane32_swap_b32 %0, %1" : "+v"(a0), "+v"(a2));
        asm volatile("v_permlane16_swap_b32 %0, %1" : "+v"(a0), "+v"(a2));
        asm volatile("v_permlane32_swap_b32 %0, %1" : "+v"(a1), "+v"(a3));
        asm volatile("v_permlane16_swap_b32 %0, %1" : "+v"(a1), "+v"(a3));
        union { unsigned int u[4]; bf16x8 v; } P;
        P.u[0] = a0; P.u[1] = a1; P.u[2] = a2; P.u[3] = a3;
        pa[mi][kh] = P.v;
      }
    }

    // O += P.V (+ ones column accumulates denominator)
    __builtin_amdgcn_s_setprio(1);
#pragma unroll
    for (int nt = 0; nt < 5; ++nt) {
      bf16x8 vb0, vb1;
      if (nt < 4) {
        const unsigned short* vr = &Vts[buf][nt * 16 + ln16][0];
        vb0 = *(const bf16x8*)(vr + (quad ^ sw) * 8);
        vb1 = *(const bf16x8*)(vr + ((quad + 4) ^ sw) * 8);
      } else {
        vb0 = vone; vb1 = vone;
      }
#pragma unroll
      for (int mi = 0; mi < 2; ++mi) {
        O[mi][nt] = __builtin_amdgcn_mfma_f32_16x16x32_bf16(pa[mi][0], vb0, O[mi][nt], 0, 0, 0);
        O[mi][nt] = __builtin_amdgcn_mfma_f32_16x16x32_bf16(pa[mi][1], vb1, O[mi][nt], 0, 0, 0);
      }
    }
    __builtin_amdgcn_s_setprio(0);
    buf ^= 1;
  }

  int bb = bh / HEADS, h = bh % HEADS;
#pragma unroll
  for (int mi = 0; mi < 2; ++mi)
#pragma unroll
    for (int r = 0; r < 4; ++r) {
      float lsum = O[mi][4][r];
      lsum = __shfl(lsum, lane & 48);  // broadcast from ln16==0 of this quad
      float inv = 1.f / lsum;
      int token = q0 + wave * 32 + mi * 16 + quad * 4 + r;
      unsigned short* op = ctxb + ((size_t)(bb * NSEQ + token)) * DIM + h * DH;
#pragma unroll
      for (int nt = 0; nt < 4; ++nt)
        op[nt * 16 + ln16] = f2bf(O[mi][nt][r] * inv);
    }
}

// ---------------------------------------------------------------------------
extern "C" void kernel_launch(void* const* d_in, const int* in_sizes, int n_in,
                              void* d_out, int out_size, void* d_ws, size_t ws_size,
                              hipStream_t stream) {
  const float* x = (const float*)d_in[0];
  const float* w_qkv = (const float*)d_in[1];
  const float* b_qkv = (const float*)d_in[2];
  const float* w_out = (const float*)d_in[3];
  const float* b_out = (const float*)d_in[4];
  float* out = (float*)d_out;

  const size_t plane = (size_t)BH * NSEQ * DH;  // 6,291,456
  unsigned short* xb = (unsigned short*)d_ws;            // [8192][768]
  unsigned short* wqkvT = xb + plane;                    // [2304][768]
  unsigned short* woutT = wqkvT + (size_t)3 * DIM * DIM; // [768][768]
  unsigned short* Qb = woutT + (size_t)DIM * DIM;        // [bh][n][64]
  unsigned short* Kb = Qb + plane;                       // [bh][n][64]
  unsigned short* V0 = Kb + plane;                       // [bh][n][64]
  unsigned short* Vtb = V0 + plane;                      // [bh][64][n]
  unsigned short* ctxb = Vtb + plane;                    // [8192][768]

  cvt_bf16<<<dim3((int)(plane / 2048)), 256, 0, stream>>>(x, xb, (int)plane);
  transpose_cvt<<<dim3(3 * DIM / 32, DIM / 32), 256, 0, stream>>>(w_qkv, wqkvT, DIM, 3 * DIM);
  transpose_cvt<<<dim3(DIM / 32, DIM / 32), 256, 0, stream>>>(w_out, woutT, DIM, DIM);

  gemm_bt<128><<<dim3(3 * DIM / 128, BATCH * NSEQ / 128), 256, 0, stream>>>(
      xb, wqkvT, b_qkv, nullptr, Qb, Kb, V0, BATCH * NSEQ, 3 * DIM, DIM, 0);

  vtrans<<<dim3(NSEQ / 64, BH), 256, 0, stream>>>(V0, Vtb);

  attn_mfma4<<<dim3(NSEQ / 128, BH), 256, 0, stream>>>(Qb, Kb, Vtb, ctxb);

  gemm_bt<64><<<dim3(DIM / 128, BATCH * NSEQ / 64), 256, 0, stream>>>(
      ctxb, woutT, b_out, out, nullptr, nullptr, nullptr, BATCH * NSEQ, DIM, DIM, 1);
}

// Round 2
// 273.984 us; speedup vs baseline: 1.6427x; 1.5492x over previous
//
#include <hip/hip_runtime.h>
#include <math.h>

#define DIM 768
#define HEADS 12
#define DH 64
#define NSEQ 4096
#define BATCH 2
#define BH (BATCH * HEADS)

typedef __attribute__((ext_vector_type(8))) short bf16x8;
typedef __attribute__((ext_vector_type(4))) float f32x4;

typedef const __attribute__((address_space(1))) unsigned char* as1_u8;
typedef __attribute__((address_space(3))) unsigned char* as3_u8;

// round-half-up bf16: <=0.5 ULP, 2 VALU ops
__device__ __forceinline__ unsigned short f2bf(float x) {
  return (unsigned short)((__float_as_uint(x) + 0x8000u) >> 16);
}

// raw v_exp_f32 = 2^x. s_nop 0 covers the trans->VALU 1-wait-state hazard.
__device__ __forceinline__ float exp2_fast(float x) {
  float r;
  asm volatile("v_exp_f32 %0, %1\n\ts_nop 0" : "=v"(r) : "v"(x));
  return r;
}

// async global->LDS DMA, 16B per lane; LDS dest = wave-uniform base + lane*16
__device__ __forceinline__ void gl16(const void* g, void* l) {
  __builtin_amdgcn_global_load_lds((as1_u8)g, (as3_u8)l, 16, 0, 0);
}

// ---------------------------------------------------------------------------
// fp32 -> bf16 elementwise (x). 8 elems/thread.
// ---------------------------------------------------------------------------
__global__ __launch_bounds__(256) void cvt_bf16(const float* __restrict__ in,
                                                unsigned short* __restrict__ out,
                                                int n) {
  int i = (blockIdx.x * 256 + threadIdx.x) * 8;
  if (i >= n) return;
  float4 a = *(const float4*)(in + i);
  float4 b = *(const float4*)(in + i + 4);
  ushort4 v0, v1;
  v0.x = f2bf(a.x); v0.y = f2bf(a.y); v0.z = f2bf(a.z); v0.w = f2bf(a.w);
  v1.x = f2bf(b.x); v1.y = f2bf(b.y); v1.z = f2bf(b.z); v1.w = f2bf(b.w);
  *(ushort4*)(out + i) = v0;
  *(ushort4*)(out + i + 4) = v1;
}

// ---------------------------------------------------------------------------
// Transpose + convert: in [K][N] fp32 -> out [N][K] bf16. 32x32 tiles.
// ---------------------------------------------------------------------------
__global__ __launch_bounds__(256) void transpose_cvt(const float* __restrict__ in,
                                                     unsigned short* __restrict__ out,
                                                     int K, int N) {
  __shared__ unsigned short s[32][34];
  int t = threadIdx.x;
  int tx = t & 31, ty = t >> 5;
  int n0 = blockIdx.x * 32, k0 = blockIdx.y * 32;
#pragma unroll
  for (int i = 0; i < 4; ++i) {
    int r = ty + i * 8;
    s[r][tx] = f2bf(in[(size_t)(k0 + r) * N + n0 + tx]);
  }
  __syncthreads();
#pragma unroll
  for (int i = 0; i < 4; ++i) {
    int r = ty + i * 8;
    out[(size_t)(n0 + r) * K + k0 + tx] = s[tx][r];
  }
}

// ---------------------------------------------------------------------------
// V [bh][n][64] -> Vt [bh][64][n], bf16, 64x64 LDS tiles.
// ---------------------------------------------------------------------------
__global__ __launch_bounds__(256) void vtrans(const unsigned short* __restrict__ Vb,
                                              unsigned short* __restrict__ Vt) {
  __shared__ unsigned short s[64][72];
  int t = threadIdx.x;
  int bh = blockIdx.y;
  int n0 = blockIdx.x * 64;
  const unsigned short* src = Vb + ((size_t)bh * NSEQ + n0) * DH;
#pragma unroll
  for (int i = 0; i < 2; ++i) {
    int idx = t + i * 256;
    int row = idx >> 3, ch = (idx & 7) * 8;
    *(uint4*)&s[row][ch] = *(const uint4*)(src + (size_t)row * DH + ch);
  }
  __syncthreads();
  unsigned short* dst = Vt + (size_t)bh * DH * NSEQ + n0;
#pragma unroll
  for (int i = 0; i < 2; ++i) {
    int idx = t + i * 256;
    int dh = idx >> 3, ch = (idx & 7) * 8;
    unsigned short tmp[8];
#pragma unroll
    for (int j = 0; j < 8; ++j) tmp[j] = s[ch + j][dh];
    *(uint4*)&dst[(size_t)dh * NSEQ + ch] = *(uint4*)tmp;
  }
}

// ---------------------------------------------------------------------------
// bf16 MFMA GEMM v2: C[M,N] = A[M,K] @ Bt[N,K]^T + bias.
// m97 structure: global_load_lds (16B DMA) into linear LDS [rows][64],
// content XOR-chunk-swizzled via pre-swizzled global source; 2 barriers per
// K-step, no register staging, no ds_write. XCD-aware block swizzle.
// mode 0 (QKV): epilogue via fp32 LDS scratch (overlaying As+Bs) ->
// Qb(scaled)/Kb/V0 [bh][n][64] bf16. mode 1: fp32 row-major out.
// ---------------------------------------------------------------------------
template <int TM>
__global__ __launch_bounds__(256) void gemm_bt(
    const unsigned short* __restrict__ A, const unsigned short* __restrict__ Bt,
    const float* __restrict__ bias, float* __restrict__ outf,
    unsigned short* __restrict__ Qb, unsigned short* __restrict__ Kb,
    unsigned short* __restrict__ V0, int M, int N, int K, int mode) {
  __shared__ unsigned short S[(TM + 128) * 64];  // As | Bs, linear (DMA dest)
  unsigned short* As = S;
  unsigned short* Bs = S + TM * 64;
  constexpr int MI = TM / 32;
  const int t = threadIdx.x;
  const int wave = t >> 6, lane = t & 63;
  const int ln16 = lane & 15, quad = lane >> 4;
  const int sw = ln16 & 7;

  // XCD-aware swizzle: each XCD gets a contiguous chunk of work ids.
  const int nbx = gridDim.x;
  const int nwg = nbx * gridDim.y;
  int bid = blockIdx.x + blockIdx.y * nbx;
  int nbid = (bid & 7) * (nwg >> 3) + (bid >> 3);  // nwg % 8 == 0 for both gemms
  const int cb = nbid % nbx, rb = nbid / nbx;

  const int rw = (wave >> 1) * (TM / 2);
  const int cw = (wave & 1) * 64;

  // DMA geometry: one gl16 covers 8 rows x 128B. row8 = lane>>3, chunk lane&7.
  // Source chunk pre-swizzled so LDS[row][c] = true[row][c ^ (row&7)].
  const int row8 = lane >> 3;
  const int csw = (lane & 7) ^ row8;

  f32x4 acc[MI][4];
#pragma unroll
  for (int i = 0; i < MI; ++i)
#pragma unroll
    for (int j = 0; j < 4; ++j) acc[i][j] = (f32x4){0.f, 0.f, 0.f, 0.f};

  const unsigned short* gA = A + (size_t)(rb * TM + row8) * K + csw * 8;
  const unsigned short* gB = Bt + (size_t)(cb * 128 + row8) * K + csw * 8;

  for (int k0 = 0; k0 < K; k0 += 64) {
    __syncthreads();  // previous tile fully consumed
#pragma unroll
    for (int i = 0; i < MI; ++i) {
      int rr = wave * (TM / 4) + i * 8;
      gl16(gA + (size_t)rr * K + k0, &As[rr * 64]);
    }
#pragma unroll
    for (int i = 0; i < 4; ++i) {
      int rr = wave * 32 + i * 8;
      gl16(gB + (size_t)rr * K + k0, &Bs[rr * 64]);
    }
    asm volatile("s_waitcnt vmcnt(0)" ::: "memory");
    __syncthreads();  // tile visible to all waves

#pragma unroll
    for (int kh = 0; kh < 2; ++kh) {
      bf16x8 a[MI], b[4];
#pragma unroll
      for (int mi = 0; mi < MI; ++mi) {
        int row = rw + mi * 16 + ln16;
        a[mi] = *(const bf16x8*)&As[row * 64 + (((kh << 2) | quad) ^ sw) * 8];
      }
#pragma unroll
      for (int ni = 0; ni < 4; ++ni) {
        int row = cw + ni * 16 + ln16;
        b[ni] = *(const bf16x8*)&Bs[row * 64 + (((kh << 2) | quad) ^ sw) * 8];
      }
#pragma unroll
      for (int mi = 0; mi < MI; ++mi)
#pragma unroll
        for (int ni = 0; ni < 4; ++ni)
          acc[mi][ni] = __builtin_amdgcn_mfma_f32_16x16x32_bf16(a[mi], b[ni],
                                                                acc[mi][ni], 0, 0, 0);
    }
  }

  if (mode == 0) {
    __syncthreads();  // all waves done with LDS tiles; reuse as fp32 C-scratch
    // 768^-0.5 * log2(e): attention uses raw v_exp_f32 (2^x), so the log2e
    // factor is folded into the Q scale here. exp2(S*log2e) == exp(S).
    const float scale = 0.0520587731f;
    int col0abs = cb * 128 + cw;                 // multiple of 64
    int which = (col0abs >= 2 * DIM) ? 2 : ((col0abs >= DIM) ? 1 : 0);
    int h = (col0abs - which * DIM) >> 6;        // wave covers one full head
    unsigned short* dstp = (which == 0) ? Qb : ((which == 1) ? Kb : V0);
    const float mul = (which == 0) ? scale : 1.f;
    float* Cs = (float*)S + wave * (16 * 68);    // 16 rows x 68 floats per wave
    float bvv[4];
#pragma unroll
    for (int ni = 0; ni < 4; ++ni) bvv[ni] = bias[col0abs + ni * 16 + ln16];
#pragma unroll
    for (int mi = 0; mi < MI; ++mi) {
#pragma unroll
      for (int ni = 0; ni < 4; ++ni)
#pragma unroll
        for (int r = 0; r < 4; ++r)
          Cs[(quad * 4 + r) * 68 + ni * 16 + ln16] = (acc[mi][ni][r] + bvv[ni]) * mul;
      __asm__ volatile("s_waitcnt lgkmcnt(0)" ::: "memory");  // wave-local region
      int token = rb * TM + rw + mi * 16 + ln16;
      int bb = token >> 12, nn = token & (NSEQ - 1);
      const float* src = &Cs[ln16 * 68 + quad * 16];
      float4 c0 = *(const float4*)(src + 0);
      float4 c1 = *(const float4*)(src + 4);
      float4 c2 = *(const float4*)(src + 8);
      float4 c3 = *(const float4*)(src + 12);
      unsigned short tmp[16];
      tmp[0] = f2bf(c0.x);  tmp[1] = f2bf(c0.y);  tmp[2] = f2bf(c0.z);  tmp[3] = f2bf(c0.w);
      tmp[4] = f2bf(c1.x);  tmp[5] = f2bf(c1.y);  tmp[6] = f2bf(c1.z);  tmp[7] = f2bf(c1.w);
      tmp[8] = f2bf(c2.x);  tmp[9] = f2bf(c2.y);  tmp[10] = f2bf(c2.z); tmp[11] = f2bf(c2.w);
      tmp[12] = f2bf(c3.x); tmp[13] = f2bf(c3.y); tmp[14] = f2bf(c3.z); tmp[15] = f2bf(c3.w);
      unsigned short* dp =
          dstp + ((size_t)(bb * HEADS + h) * NSEQ + nn) * DH + quad * 16;
      *(uint4*)&dp[0] = *(uint4*)&tmp[0];
      *(uint4*)&dp[8] = *(uint4*)&tmp[8];
      __asm__ volatile("s_waitcnt lgkmcnt(0)" ::: "memory");  // reads done before next mi writes
    }
  } else {
#pragma unroll
    for (int ni = 0; ni < 4; ++ni) {
      int col = cb * 128 + cw + ni * 16 + ln16;
      float bv2 = bias[col];
#pragma unroll
      for (int mi = 0; mi < MI; ++mi)
#pragma unroll
        for (int r = 0; r < 4; ++r) {
          int token = rb * TM + rw + mi * 16 + quad * 4 + r;
          outf[(size_t)token * N + col] = acc[mi][ni][r] + bv2;
        }
    }
  }
}

// ---------------------------------------------------------------------------
// MFMA flash attention v4: swapped QK^T + in-register P exchange
// (cvt_pk_bf16 + permlane swaps), global_load_lds double-buffered staging
// (1 barrier/tile), register ones-fragment denominator, exp2 with log2e
// folded into Q scale upstream. v4.1: XCD-aware block swizzle (3 heads'
// K/V per XCD -> fits 4MB L2).
// ---------------------------------------------------------------------------
__global__ __launch_bounds__(256, 3) void attn_mfma4(
    const unsigned short* __restrict__ Qg, const unsigned short* __restrict__ Kg,
    const unsigned short* __restrict__ Vtg, unsigned short* __restrict__ ctxb) {
  __shared__ unsigned short Ks[2][64][64];   // [buf][key][dh], chunk-XOR-swizzled
  __shared__ unsigned short Vts[2][64][64];  // [buf][dh][key], chunk-XOR-swizzled

  const int t = threadIdx.x;
  const int wave = t >> 6, lane = t & 63;
  const int ln16 = lane & 15, quad = lane >> 4;

  // XCD swizzle: nwg = 32*24 = 768, 96 per XCD = 3 heads x 32 q-blocks.
  int bid = blockIdx.x + blockIdx.y * 32;
  int nbid = (bid & 7) * 96 + (bid >> 3);
  const int bh = nbid >> 5;
  const int q0 = (nbid & 31) * 128;

  // Q fragments (registers, whole kernel)
  const unsigned short* Qp = Qg + ((size_t)bh * NSEQ + q0 + wave * 32) * DH;
  bf16x8 qf[2][2];
#pragma unroll
  for (int mi = 0; mi < 2; ++mi)
#pragma unroll
    for (int kh = 0; kh < 2; ++kh)
      qf[mi][kh] = *(const bf16x8*)(Qp + (size_t)(mi * 16 + ln16) * DH + kh * 32 + quad * 8);

  f32x4 O[2][5];
#pragma unroll
  for (int mi = 0; mi < 2; ++mi)
#pragma unroll
    for (int nt = 0; nt < 5; ++nt) O[mi][nt] = (f32x4){0.f, 0.f, 0.f, 0.f};

  const unsigned short* Kbase = Kg + (size_t)bh * NSEQ * DH;
  const unsigned short* Vbase = Vtg + (size_t)bh * DH * NSEQ;

  // staging geometry: per gl16 a wave covers 8 rows x 128B; row = lane>>3,
  // chunk = lane&7. Source chunk pre-swizzled by row&7 so that
  // LDS[row][c] = true[row][c ^ (row&7)] (16B-chunk XOR swizzle).
  const int row8 = lane >> 3;
  const int csw = (lane & 7) ^ row8;

  auto stage = [&](int b, int kk) {
#pragma unroll
    for (int i = 0; i < 2; ++i) {
      int rr = wave * 16 + i * 8;
      gl16(Kbase + (size_t)(kk + rr + row8) * DH + csw * 8, &Ks[b][rr][0]);
      gl16(Vbase + (size_t)(rr + row8) * NSEQ + kk + csw * 8, &Vts[b][rr][0]);
    }
  };

  // ones B-fragment for denominator column (row 0 of B = ones)
  union { unsigned int u[4]; bf16x8 v; } VO;
  {
    unsigned int ow = (ln16 == 0) ? 0x3F803F80u : 0u;
    VO.u[0] = ow; VO.u[1] = ow; VO.u[2] = ow; VO.u[3] = ow;
  }
  const bf16x8 vone = VO.v;

  stage(0, 0);
  const int sw = ln16 & 7;
  int buf = 0;

  for (int k0 = 0; k0 < NSEQ; k0 += 64) {
    asm volatile("s_waitcnt vmcnt(0)" ::: "memory");  // own DMA done
    __syncthreads();                                  // everyone's DMA done; prev tile consumed
    if (k0 + 64 < NSEQ) stage(buf ^ 1, k0 + 64);      // prefetch DMA under this tile's compute

    // S~ = K.Q^T  (swapped operands: col=ln16=query, row=quad*4+r=key)
    f32x4 S[2][4];
    __builtin_amdgcn_s_setprio(1);
#pragma unroll
    for (int nt = 0; nt < 4; ++nt) {
      const unsigned short* kr = &Ks[buf][nt * 16 + ln16][0];
      bf16x8 kb0 = *(const bf16x8*)(kr + (quad ^ sw) * 8);
      bf16x8 kb1 = *(const bf16x8*)(kr + ((quad + 4) ^ sw) * 8);
#pragma unroll
      for (int mi = 0; mi < 2; ++mi) {
        f32x4 s = (f32x4){0.f, 0.f, 0.f, 0.f};
        s = __builtin_amdgcn_mfma_f32_16x16x32_bf16(kb0, qf[mi][0], s, 0, 0, 0);
        s = __builtin_amdgcn_mfma_f32_16x16x32_bf16(kb1, qf[mi][1], s, 0, 0, 0);
        S[mi][nt] = s;
      }
    }
    __builtin_amdgcn_s_setprio(0);

    // P = exp2(S~) -> bf16 pack -> in-register quad exchange -> PV A-frags.
    bf16x8 pa[2][2];
#pragma unroll
    for (int mi = 0; mi < 2; ++mi) {
      unsigned int c[4][2];
#pragma unroll
      for (int nt = 0; nt < 4; ++nt) {
        float e0 = exp2_fast(S[mi][nt][0]);
        float e1 = exp2_fast(S[mi][nt][1]);
        float e2 = exp2_fast(S[mi][nt][2]);
        float e3 = exp2_fast(S[mi][nt][3]);
        asm volatile("v_cvt_pk_bf16_f32 %0, %1, %2" : "=v"(c[nt][0]) : "v"(e0), "v"(e1));
        asm volatile("v_cvt_pk_bf16_f32 %0, %1, %2" : "=v"(c[nt][1]) : "v"(e2), "v"(e3));
      }
#pragma unroll
      for (int kh = 0; kh < 2; ++kh) {
        unsigned int a0 = c[2 * kh][0], a1 = c[2 * kh][1];
        unsigned int a2 = c[2 * kh + 1][0], a3 = c[2 * kh + 1][1];
        asm volatile("v_permlane32_swap_b32 %0, %1" : "+v"(a0), "+v"(a2));
        asm volatile("v_permlane16_swap_b32 %0, %1" : "+v"(a0), "+v"(a2));
        asm volatile("v_permlane32_swap_b32 %0, %1" : "+v"(a1), "+v"(a3));
        asm volatile("v_permlane16_swap_b32 %0, %1" : "+v"(a1), "+v"(a3));
        union { unsigned int u[4]; bf16x8 v; } P;
        P.u[0] = a0; P.u[1] = a1; P.u[2] = a2; P.u[3] = a3;
        pa[mi][kh] = P.v;
      }
    }

    // O += P.V (+ ones column accumulates denominator)
    __builtin_amdgcn_s_setprio(1);
#pragma unroll
    for (int nt = 0; nt < 5; ++nt) {
      bf16x8 vb0, vb1;
      if (nt < 4) {
        const unsigned short* vr = &Vts[buf][nt * 16 + ln16][0];
        vb0 = *(const bf16x8*)(vr + (quad ^ sw) * 8);
        vb1 = *(const bf16x8*)(vr + ((quad + 4) ^ sw) * 8);
      } else {
        vb0 = vone; vb1 = vone;
      }
#pragma unroll
      for (int mi = 0; mi < 2; ++mi) {
        O[mi][nt] = __builtin_amdgcn_mfma_f32_16x16x32_bf16(pa[mi][0], vb0, O[mi][nt], 0, 0, 0);
        O[mi][nt] = __builtin_amdgcn_mfma_f32_16x16x32_bf16(pa[mi][1], vb1, O[mi][nt], 0, 0, 0);
      }
    }
    __builtin_amdgcn_s_setprio(0);
    buf ^= 1;
  }

  int bb = bh / HEADS, h = bh % HEADS;
#pragma unroll
  for (int mi = 0; mi < 2; ++mi)
#pragma unroll
    for (int r = 0; r < 4; ++r) {
      float lsum = O[mi][4][r];
      lsum = __shfl(lsum, lane & 48);  // broadcast from ln16==0 of this quad
      float inv = 1.f / lsum;
      int token = q0 + wave * 32 + mi * 16 + quad * 4 + r;
      unsigned short* op = ctxb + ((size_t)(bb * NSEQ + token)) * DIM + h * DH;
#pragma unroll
      for (int nt = 0; nt < 4; ++nt)
        op[nt * 16 + ln16] = f2bf(O[mi][nt][r] * inv);
    }
}

// ---------------------------------------------------------------------------
extern "C" void kernel_launch(void* const* d_in, const int* in_sizes, int n_in,
                              void* d_out, int out_size, void* d_ws, size_t ws_size,
                              hipStream_t stream) {
  const float* x = (const float*)d_in[0];
  const float* w_qkv = (const float*)d_in[1];
  const float* b_qkv = (const float*)d_in[2];
  const float* w_out = (const float*)d_in[3];
  const float* b_out = (const float*)d_in[4];
  float* out = (float*)d_out;

  const size_t plane = (size_t)BH * NSEQ * DH;  // 6,291,456
  unsigned short* xb = (unsigned short*)d_ws;            // [8192][768]
  unsigned short* wqkvT = xb + plane;                    // [2304][768]
  unsigned short* woutT = wqkvT + (size_t)3 * DIM * DIM; // [768][768]
  unsigned short* Qb = woutT + (size_t)DIM * DIM;        // [bh][n][64]
  unsigned short* Kb = Qb + plane;                       // [bh][n][64]
  unsigned short* V0 = Kb + plane;                       // [bh][n][64]
  unsigned short* Vtb = V0 + plane;                      // [bh][64][n]
  unsigned short* ctxb = Vtb + plane;                    // [8192][768]

  cvt_bf16<<<dim3((int)(plane / 2048)), 256, 0, stream>>>(x, xb, (int)plane);
  transpose_cvt<<<dim3(3 * DIM / 32, DIM / 32), 256, 0, stream>>>(w_qkv, wqkvT, DIM, 3 * DIM);
  transpose_cvt<<<dim3(DIM / 32, DIM / 32), 256, 0, stream>>>(w_out, woutT, DIM, DIM);

  gemm_bt<128><<<dim3(3 * DIM / 128, BATCH * NSEQ / 128), 256, 0, stream>>>(
      xb, wqkvT, b_qkv, nullptr, Qb, Kb, V0, BATCH * NSEQ, 3 * DIM, DIM, 0);

  vtrans<<<dim3(NSEQ / 64, BH), 256, 0, stream>>>(V0, Vtb);

  attn_mfma4<<<dim3(NSEQ / 128, BH), 256, 0, stream>>>(Qb, Kb, Vtb, ctxb);

  gemm_bt<64><<<dim3(DIM / 128, BATCH * NSEQ / 64), 256, 0, stream>>>(
      ctxb, woutT, b_out, out, nullptr, nullptr, nullptr, BATCH * NSEQ, DIM, DIM, 1);
}

// Round 3
// 258.862 us; speedup vs baseline: 1.7387x; 1.0584x over previous
//
#include <hip/hip_runtime.h>
#include <math.h>

#define DIM 768
#define HEADS 12
#define DH 64
#define NSEQ 4096
#define BATCH 2
#define BH (BATCH * HEADS)

typedef __attribute__((ext_vector_type(8))) short bf16x8;
typedef __attribute__((ext_vector_type(4))) float f32x4;

typedef const __attribute__((address_space(1))) unsigned char* as1_u8;
typedef __attribute__((address_space(3))) unsigned char* as3_u8;

// round-half-up bf16: <=0.5 ULP, 2 VALU ops
__device__ __forceinline__ unsigned short f2bf(float x) {
  return (unsigned short)((__float_as_uint(x) + 0x8000u) >> 16);
}

// async global->LDS DMA, 16B per lane; LDS dest = wave-uniform base + lane*16
__device__ __forceinline__ void gl16(const void* g, void* l) {
  __builtin_amdgcn_global_load_lds((as1_u8)g, (as3_u8)l, 16, 0, 0);
}

// ---------------------------------------------------------------------------
// fp32 -> bf16 elementwise (x). 8 elems/thread.
// ---------------------------------------------------------------------------
__global__ __launch_bounds__(256) void cvt_bf16(const float* __restrict__ in,
                                                unsigned short* __restrict__ out,
                                                int n) {
  int i = (blockIdx.x * 256 + threadIdx.x) * 8;
  if (i >= n) return;
  float4 a = *(const float4*)(in + i);
  float4 b = *(const float4*)(in + i + 4);
  ushort4 v0, v1;
  v0.x = f2bf(a.x); v0.y = f2bf(a.y); v0.z = f2bf(a.z); v0.w = f2bf(a.w);
  v1.x = f2bf(b.x); v1.y = f2bf(b.y); v1.z = f2bf(b.z); v1.w = f2bf(b.w);
  *(ushort4*)(out + i) = v0;
  *(ushort4*)(out + i + 4) = v1;
}

// ---------------------------------------------------------------------------
// Transpose + convert: in [K][N] fp32 -> out [N][K] bf16. 32x32 tiles.
// ---------------------------------------------------------------------------
__global__ __launch_bounds__(256) void transpose_cvt(const float* __restrict__ in,
                                                     unsigned short* __restrict__ out,
                                                     int K, int N) {
  __shared__ unsigned short s[32][34];
  int t = threadIdx.x;
  int tx = t & 31, ty = t >> 5;
  int n0 = blockIdx.x * 32, k0 = blockIdx.y * 32;
#pragma unroll
  for (int i = 0; i < 4; ++i) {
    int r = ty + i * 8;
    s[r][tx] = f2bf(in[(size_t)(k0 + r) * N + n0 + tx]);
  }
  __syncthreads();
#pragma unroll
  for (int i = 0; i < 4; ++i) {
    int r = ty + i * 8;
    out[(size_t)(n0 + r) * K + k0 + tx] = s[tx][r];
  }
}

// ---------------------------------------------------------------------------
// V [bh][n][64] -> Vt [bh][64][n], bf16, 64x64 LDS tiles.
// ---------------------------------------------------------------------------
__global__ __launch_bounds__(256) void vtrans(const unsigned short* __restrict__ Vb,
                                              unsigned short* __restrict__ Vt) {
  __shared__ unsigned short s[64][72];
  int t = threadIdx.x;
  int bh = blockIdx.y;
  int n0 = blockIdx.x * 64;
  const unsigned short* src = Vb + ((size_t)bh * NSEQ + n0) * DH;
#pragma unroll
  for (int i = 0; i < 2; ++i) {
    int idx = t + i * 256;
    int row = idx >> 3, ch = (idx & 7) * 8;
    *(uint4*)&s[row][ch] = *(const uint4*)(src + (size_t)row * DH + ch);
  }
  __syncthreads();
  unsigned short* dst = Vt + (size_t)bh * DH * NSEQ + n0;
#pragma unroll
  for (int i = 0; i < 2; ++i) {
    int idx = t + i * 256;
    int dh = idx >> 3, ch = (idx & 7) * 8;
    unsigned short tmp[8];
#pragma unroll
    for (int j = 0; j < 8; ++j) tmp[j] = s[ch + j][dh];
    *(uint4*)&dst[(size_t)dh * NSEQ + ch] = *(uint4*)tmp;
  }
}

// ---------------------------------------------------------------------------
// bf16 MFMA GEMM v2: C[M,N] = A[M,K] @ Bt[N,K]^T + bias.
// m97 structure: global_load_lds (16B DMA) into linear LDS [rows][64],
// content XOR-chunk-swizzled via pre-swizzled global source; 2 barriers per
// K-step, no register staging, no ds_write. XCD-aware block swizzle.
// mode 0 (QKV): epilogue via fp32 LDS scratch (overlaying As+Bs) ->
// Qb(scaled)/Kb/V0 [bh][n][64] bf16. mode 1: fp32 row-major out.
// ---------------------------------------------------------------------------
template <int TM>
__global__ __launch_bounds__(256, 4) void gemm_bt(
    const unsigned short* __restrict__ A, const unsigned short* __restrict__ Bt,
    const float* __restrict__ bias, float* __restrict__ outf,
    unsigned short* __restrict__ Qb, unsigned short* __restrict__ Kb,
    unsigned short* __restrict__ V0, int M, int N, int K, int mode) {
  __shared__ unsigned short S[(TM + 128) * 64];  // As | Bs, linear (DMA dest)
  unsigned short* As = S;
  unsigned short* Bs = S + TM * 64;
  constexpr int MI = TM / 32;
  const int t = threadIdx.x;
  const int wave = t >> 6, lane = t & 63;
  const int ln16 = lane & 15, quad = lane >> 4;
  const int sw = ln16 & 7;

  // XCD-aware swizzle: each XCD gets a contiguous chunk of work ids.
  const int nbx = gridDim.x;
  const int nwg = nbx * gridDim.y;
  int bid = blockIdx.x + blockIdx.y * nbx;
  int nbid = (bid & 7) * (nwg >> 3) + (bid >> 3);  // nwg % 8 == 0 for both gemms
  const int cb = nbid % nbx, rb = nbid / nbx;

  const int rw = (wave >> 1) * (TM / 2);
  const int cw = (wave & 1) * 64;

  // DMA geometry: one gl16 covers 8 rows x 128B. row8 = lane>>3, chunk lane&7.
  // Source chunk pre-swizzled so LDS[row][c] = true[row][c ^ (row&7)].
  const int row8 = lane >> 3;
  const int csw = (lane & 7) ^ row8;

  f32x4 acc[MI][4];
#pragma unroll
  for (int i = 0; i < MI; ++i)
#pragma unroll
    for (int j = 0; j < 4; ++j) acc[i][j] = (f32x4){0.f, 0.f, 0.f, 0.f};

  const unsigned short* gA = A + (size_t)(rb * TM + row8) * K + csw * 8;
  const unsigned short* gB = Bt + (size_t)(cb * 128 + row8) * K + csw * 8;

  for (int k0 = 0; k0 < K; k0 += 64) {
    __syncthreads();  // previous tile fully consumed
#pragma unroll
    for (int i = 0; i < MI; ++i) {
      int rr = wave * (TM / 4) + i * 8;
      gl16(gA + (size_t)rr * K + k0, &As[rr * 64]);
    }
#pragma unroll
    for (int i = 0; i < 4; ++i) {
      int rr = wave * 32 + i * 8;
      gl16(gB + (size_t)rr * K + k0, &Bs[rr * 64]);
    }
    asm volatile("s_waitcnt vmcnt(0)" ::: "memory");
    __syncthreads();  // tile visible to all waves

#pragma unroll
    for (int kh = 0; kh < 2; ++kh) {
      bf16x8 a[MI], b[4];
#pragma unroll
      for (int mi = 0; mi < MI; ++mi) {
        int row = rw + mi * 16 + ln16;
        a[mi] = *(const bf16x8*)&As[row * 64 + (((kh << 2) | quad) ^ sw) * 8];
      }
#pragma unroll
      for (int ni = 0; ni < 4; ++ni) {
        int row = cw + ni * 16 + ln16;
        b[ni] = *(const bf16x8*)&Bs[row * 64 + (((kh << 2) | quad) ^ sw) * 8];
      }
#pragma unroll
      for (int mi = 0; mi < MI; ++mi)
#pragma unroll
        for (int ni = 0; ni < 4; ++ni)
          acc[mi][ni] = __builtin_amdgcn_mfma_f32_16x16x32_bf16(a[mi], b[ni],
                                                                acc[mi][ni], 0, 0, 0);
    }
  }

  if (mode == 0) {
    __syncthreads();  // all waves done with LDS tiles; reuse as fp32 C-scratch
    // 768^-0.5 * log2(e): attention uses raw v_exp_f32 (2^x), so the log2e
    // factor is folded into the Q scale here. exp2(S*log2e) == exp(S).
    const float scale = 0.0520587731f;
    int col0abs = cb * 128 + cw;                 // multiple of 64
    int which = (col0abs >= 2 * DIM) ? 2 : ((col0abs >= DIM) ? 1 : 0);
    int h = (col0abs - which * DIM) >> 6;        // wave covers one full head
    unsigned short* dstp = (which == 0) ? Qb : ((which == 1) ? Kb : V0);
    const float mul = (which == 0) ? scale : 1.f;
    float* Cs = (float*)S + wave * (16 * 68);    // 16 rows x 68 floats per wave
    float bvv[4];
#pragma unroll
    for (int ni = 0; ni < 4; ++ni) bvv[ni] = bias[col0abs + ni * 16 + ln16];
#pragma unroll
    for (int mi = 0; mi < MI; ++mi) {
#pragma unroll
      for (int ni = 0; ni < 4; ++ni)
#pragma unroll
        for (int r = 0; r < 4; ++r)
          Cs[(quad * 4 + r) * 68 + ni * 16 + ln16] = (acc[mi][ni][r] + bvv[ni]) * mul;
      __asm__ volatile("s_waitcnt lgkmcnt(0)" ::: "memory");  // wave-local region
      int token = rb * TM + rw + mi * 16 + ln16;
      int bb = token >> 12, nn = token & (NSEQ - 1);
      const float* src = &Cs[ln16 * 68 + quad * 16];
      float4 c0 = *(const float4*)(src + 0);
      float4 c1 = *(const float4*)(src + 4);
      float4 c2 = *(const float4*)(src + 8);
      float4 c3 = *(const float4*)(src + 12);
      unsigned short tmp[16];
      tmp[0] = f2bf(c0.x);  tmp[1] = f2bf(c0.y);  tmp[2] = f2bf(c0.z);  tmp[3] = f2bf(c0.w);
      tmp[4] = f2bf(c1.x);  tmp[5] = f2bf(c1.y);  tmp[6] = f2bf(c1.z);  tmp[7] = f2bf(c1.w);
      tmp[8] = f2bf(c2.x);  tmp[9] = f2bf(c2.y);  tmp[10] = f2bf(c2.z); tmp[11] = f2bf(c2.w);
      tmp[12] = f2bf(c3.x); tmp[13] = f2bf(c3.y); tmp[14] = f2bf(c3.z); tmp[15] = f2bf(c3.w);
      unsigned short* dp =
          dstp + ((size_t)(bb * HEADS + h) * NSEQ + nn) * DH + quad * 16;
      *(uint4*)&dp[0] = *(uint4*)&tmp[0];
      *(uint4*)&dp[8] = *(uint4*)&tmp[8];
      __asm__ volatile("s_waitcnt lgkmcnt(0)" ::: "memory");  // reads done before next mi writes
    }
  } else {
#pragma unroll
    for (int ni = 0; ni < 4; ++ni) {
      int col = cb * 128 + cw + ni * 16 + ln16;
      float bv2 = bias[col];
#pragma unroll
      for (int mi = 0; mi < MI; ++mi)
#pragma unroll
        for (int r = 0; r < 4; ++r) {
          int token = rb * TM + rw + mi * 16 + quad * 4 + r;
          outf[(size_t)token * N + col] = acc[mi][ni][r] + bv2;
        }
    }
  }
}

// ---------------------------------------------------------------------------
// MFMA flash attention v5. vs v4:
//  * exp2 via __builtin_amdgcn_exp2f (compiler-managed trans hazard, no s_nop,
//    schedulable) - was 32 volatile asm {v_exp; s_nop} pairs per tile.
//  * cvt_pk/permlane asm non-volatile: scheduler may interleave with MFMA
//    shadow instead of inserting v_mov fixups around tied operands.
//  * hoisted zero quad for S init (no per-tile v_mov zeroing).
//  * 4 blocks/CU (launch_bounds(256,4); LDS 4x32KB=128KB) for latency hiding.
// ---------------------------------------------------------------------------
__global__ __launch_bounds__(256, 4) void attn_mfma5(
    const unsigned short* __restrict__ Qg, const unsigned short* __restrict__ Kg,
    const unsigned short* __restrict__ Vtg, unsigned short* __restrict__ ctxb) {
  __shared__ unsigned short Ks[2][64][64];   // [buf][key][dh], chunk-XOR-swizzled
  __shared__ unsigned short Vts[2][64][64];  // [buf][dh][key], chunk-XOR-swizzled

  const int t = threadIdx.x;
  const int wave = t >> 6, lane = t & 63;
  const int ln16 = lane & 15, quad = lane >> 4;

  // XCD swizzle: nwg = 32*24 = 768, 96 per XCD = 3 heads x 32 q-blocks.
  int bid = blockIdx.x + blockIdx.y * 32;
  int nbid = (bid & 7) * 96 + (bid >> 3);
  const int bh = nbid >> 5;
  const int q0 = (nbid & 31) * 128;

  // Q fragments (registers, whole kernel)
  const unsigned short* Qp = Qg + ((size_t)bh * NSEQ + q0 + wave * 32) * DH;
  bf16x8 qf[2][2];
#pragma unroll
  for (int mi = 0; mi < 2; ++mi)
#pragma unroll
    for (int kh = 0; kh < 2; ++kh)
      qf[mi][kh] = *(const bf16x8*)(Qp + (size_t)(mi * 16 + ln16) * DH + kh * 32 + quad * 8);

  f32x4 O[2][5];
#pragma unroll
  for (int mi = 0; mi < 2; ++mi)
#pragma unroll
    for (int nt = 0; nt < 5; ++nt) O[mi][nt] = (f32x4){0.f, 0.f, 0.f, 0.f};

  const f32x4 z4 = (f32x4){0.f, 0.f, 0.f, 0.f};  // shared MFMA C=0 operand

  const unsigned short* Kbase = Kg + (size_t)bh * NSEQ * DH;
  const unsigned short* Vbase = Vtg + (size_t)bh * DH * NSEQ;

  // staging geometry: per gl16 a wave covers 8 rows x 128B; row = lane>>3,
  // chunk = lane&7. Source chunk pre-swizzled by row&7 so that
  // LDS[row][c] = true[row][c ^ (row&7)] (16B-chunk XOR swizzle).
  const int row8 = lane >> 3;
  const int csw = (lane & 7) ^ row8;

  auto stage = [&](int b, int kk) {
#pragma unroll
    for (int i = 0; i < 2; ++i) {
      int rr = wave * 16 + i * 8;
      gl16(Kbase + (size_t)(kk + rr + row8) * DH + csw * 8, &Ks[b][rr][0]);
      gl16(Vbase + (size_t)(rr + row8) * NSEQ + kk + csw * 8, &Vts[b][rr][0]);
    }
  };

  // ones B-fragment for denominator column (row 0 of B = ones)
  union { unsigned int u[4]; bf16x8 v; } VO;
  {
    unsigned int ow = (ln16 == 0) ? 0x3F803F80u : 0u;
    VO.u[0] = ow; VO.u[1] = ow; VO.u[2] = ow; VO.u[3] = ow;
  }
  const bf16x8 vone = VO.v;

  stage(0, 0);
  const int sw = ln16 & 7;
  int buf = 0;

  for (int k0 = 0; k0 < NSEQ; k0 += 64) {
    asm volatile("s_waitcnt vmcnt(0)" ::: "memory");  // own DMA done
    __syncthreads();                                  // everyone's DMA done; prev tile consumed
    if (k0 + 64 < NSEQ) stage(buf ^ 1, k0 + 64);      // prefetch DMA under this tile's compute

    // S~ = K.Q^T  (swapped operands: col=ln16=query, row=quad*4+r=key)
    f32x4 S[2][4];
    __builtin_amdgcn_s_setprio(1);
#pragma unroll
    for (int nt = 0; nt < 4; ++nt) {
      const unsigned short* kr = &Ks[buf][nt * 16 + ln16][0];
      bf16x8 kb0 = *(const bf16x8*)(kr + (quad ^ sw) * 8);
      bf16x8 kb1 = *(const bf16x8*)(kr + ((quad + 4) ^ sw) * 8);
#pragma unroll
      for (int mi = 0; mi < 2; ++mi) {
        f32x4 s = __builtin_amdgcn_mfma_f32_16x16x32_bf16(kb0, qf[mi][0], z4, 0, 0, 0);
        s = __builtin_amdgcn_mfma_f32_16x16x32_bf16(kb1, qf[mi][1], s, 0, 0, 0);
        S[mi][nt] = s;
      }
    }
    __builtin_amdgcn_s_setprio(0);

    // P = exp2(S~) -> bf16 pack -> in-register quad exchange -> PV A-frags.
    // Lane (ln16,quad) holds P[q=mi*16+ln16][key=nt*16+quad*4+r].
    bf16x8 pa[2][2];
#pragma unroll
    for (int mi = 0; mi < 2; ++mi) {
      unsigned int c[4][2];
#pragma unroll
      for (int nt = 0; nt < 4; ++nt) {
        float e0 = __builtin_amdgcn_exp2f(S[mi][nt][0]);
        float e1 = __builtin_amdgcn_exp2f(S[mi][nt][1]);
        float e2 = __builtin_amdgcn_exp2f(S[mi][nt][2]);
        float e3 = __builtin_amdgcn_exp2f(S[mi][nt][3]);
        asm("v_cvt_pk_bf16_f32 %0, %1, %2" : "=v"(c[nt][0]) : "v"(e0), "v"(e1));
        asm("v_cvt_pk_bf16_f32 %0, %1, %2" : "=v"(c[nt][1]) : "v"(e2), "v"(e3));
      }
#pragma unroll
      for (int kh = 0; kh < 2; ++kh) {
        unsigned int a0 = c[2 * kh][0], a1 = c[2 * kh][1];
        unsigned int a2 = c[2 * kh + 1][0], a3 = c[2 * kh + 1][1];
        asm("v_permlane32_swap_b32 %0, %1" : "+v"(a0), "+v"(a2));
        asm("v_permlane16_swap_b32 %0, %1" : "+v"(a0), "+v"(a2));
        asm("v_permlane32_swap_b32 %0, %1" : "+v"(a1), "+v"(a3));
        asm("v_permlane16_swap_b32 %0, %1" : "+v"(a1), "+v"(a3));
        union { unsigned int u[4]; bf16x8 v; } P;
        P.u[0] = a0; P.u[1] = a1; P.u[2] = a2; P.u[3] = a3;
        pa[mi][kh] = P.v;
      }
    }

    // O += P.V (+ ones column accumulates denominator)
    __builtin_amdgcn_s_setprio(1);
#pragma unroll
    for (int nt = 0; nt < 5; ++nt) {
      bf16x8 vb0, vb1;
      if (nt < 4) {
        const unsigned short* vr = &Vts[buf][nt * 16 + ln16][0];
        vb0 = *(const bf16x8*)(vr + (quad ^ sw) * 8);
        vb1 = *(const bf16x8*)(vr + ((quad + 4) ^ sw) * 8);
      } else {
        vb0 = vone; vb1 = vone;
      }
#pragma unroll
      for (int mi = 0; mi < 2; ++mi) {
        O[mi][nt] = __builtin_amdgcn_mfma_f32_16x16x32_bf16(pa[mi][0], vb0, O[mi][nt], 0, 0, 0);
        O[mi][nt] = __builtin_amdgcn_mfma_f32_16x16x32_bf16(pa[mi][1], vb1, O[mi][nt], 0, 0, 0);
      }
    }
    __builtin_amdgcn_s_setprio(0);
    buf ^= 1;
  }

  int bb = bh / HEADS, h = bh % HEADS;
#pragma unroll
  for (int mi = 0; mi < 2; ++mi)
#pragma unroll
    for (int r = 0; r < 4; ++r) {
      float lsum = O[mi][4][r];
      lsum = __shfl(lsum, lane & 48);  // broadcast from ln16==0 of this quad
      float inv = 1.f / lsum;
      int token = q0 + wave * 32 + mi * 16 + quad * 4 + r;
      unsigned short* op = ctxb + ((size_t)(bb * NSEQ + token)) * DIM + h * DH;
#pragma unroll
      for (int nt = 0; nt < 4; ++nt)
        op[nt * 16 + ln16] = f2bf(O[mi][nt][r] * inv);
    }
}

// ---------------------------------------------------------------------------
extern "C" void kernel_launch(void* const* d_in, const int* in_sizes, int n_in,
                              void* d_out, int out_size, void* d_ws, size_t ws_size,
                              hipStream_t stream) {
  const float* x = (const float*)d_in[0];
  const float* w_qkv = (const float*)d_in[1];
  const float* b_qkv = (const float*)d_in[2];
  const float* w_out = (const float*)d_in[3];
  const float* b_out = (const float*)d_in[4];
  float* out = (float*)d_out;

  const size_t plane = (size_t)BH * NSEQ * DH;  // 6,291,456
  unsigned short* xb = (unsigned short*)d_ws;            // [8192][768]
  unsigned short* wqkvT = xb + plane;                    // [2304][768]
  unsigned short* woutT = wqkvT + (size_t)3 * DIM * DIM; // [768][768]
  unsigned short* Qb = woutT + (size_t)DIM * DIM;        // [bh][n][64]
  unsigned short* Kb = Qb + plane;                       // [bh][n][64]
  unsigned short* V0 = Kb + plane;                       // [bh][n][64]
  unsigned short* Vtb = V0 + plane;                      // [bh][64][n]
  unsigned short* ctxb = Vtb + plane;                    // [8192][768]

  cvt_bf16<<<dim3((int)(plane / 2048)), 256, 0, stream>>>(x, xb, (int)plane);
  transpose_cvt<<<dim3(3 * DIM / 32, DIM / 32), 256, 0, stream>>>(w_qkv, wqkvT, DIM, 3 * DIM);
  transpose_cvt<<<dim3(DIM / 32, DIM / 32), 256, 0, stream>>>(w_out, woutT, DIM, DIM);

  gemm_bt<128><<<dim3(3 * DIM / 128, BATCH * NSEQ / 128), 256, 0, stream>>>(
      xb, wqkvT, b_qkv, nullptr, Qb, Kb, V0, BATCH * NSEQ, 3 * DIM, DIM, 0);

  vtrans<<<dim3(NSEQ / 64, BH), 256, 0, stream>>>(V0, Vtb);

  attn_mfma5<<<dim3(NSEQ / 128, BH), 256, 0, stream>>>(Qb, Kb, Vtb, ctxb);

  gemm_bt<64><<<dim3(DIM / 128, BATCH * NSEQ / 64), 256, 0, stream>>>(
      ctxb, woutT, b_out, out, nullptr, nullptr, nullptr, BATCH * NSEQ, DIM, DIM, 1);
}

// Round 4
// 256.804 us; speedup vs baseline: 1.7526x; 1.0080x over previous
//
#include <hip/hip_runtime.h>
#include <math.h>

#define DIM 768
#define HEADS 12
#define DH 64
#define NSEQ 4096
#define BATCH 2
#define BH (BATCH * HEADS)

typedef __attribute__((ext_vector_type(8))) short bf16x8;
typedef __attribute__((ext_vector_type(4))) float f32x4;

typedef const __attribute__((address_space(1))) unsigned char* as1_u8;
typedef __attribute__((address_space(3))) unsigned char* as3_u8;

// round-half-up bf16: <=0.5 ULP, 2 VALU ops
__device__ __forceinline__ unsigned short f2bf(float x) {
  return (unsigned short)((__float_as_uint(x) + 0x8000u) >> 16);
}

// raw v_exp_f32 = 2^x. s_nop 0 covers the trans->VALU 1-wait-state hazard.
__device__ __forceinline__ float exp2_fast(float x) {
  float r;
  asm volatile("v_exp_f32 %0, %1\n\ts_nop 0" : "=v"(r) : "v"(x));
  return r;
}

// async global->LDS DMA, 16B per lane; LDS dest = wave-uniform base + lane*16
__device__ __forceinline__ void gl16(const void* g, void* l) {
  __builtin_amdgcn_global_load_lds((as1_u8)g, (as3_u8)l, 16, 0, 0);
}

// ---------------------------------------------------------------------------
// Transpose + convert: in [K][N] fp32 -> out [N][K] bf16. 32x32 tiles.
// ---------------------------------------------------------------------------
__global__ __launch_bounds__(256) void transpose_cvt(const float* __restrict__ in,
                                                     unsigned short* __restrict__ out,
                                                     int K, int N) {
  __shared__ unsigned short s[32][34];
  int t = threadIdx.x;
  int tx = t & 31, ty = t >> 5;
  int n0 = blockIdx.x * 32, k0 = blockIdx.y * 32;
#pragma unroll
  for (int i = 0; i < 4; ++i) {
    int r = ty + i * 8;
    s[r][tx] = f2bf(in[(size_t)(k0 + r) * N + n0 + tx]);
  }
  __syncthreads();
#pragma unroll
  for (int i = 0; i < 4; ++i) {
    int r = ty + i * 8;
    out[(size_t)(n0 + r) * K + k0 + tx] = s[tx][r];
  }
}

// ---------------------------------------------------------------------------
// V [bh][n][64] -> Vt [bh][64][n], bf16, 64x64 LDS tiles.
// ---------------------------------------------------------------------------
__global__ __launch_bounds__(256) void vtrans(const unsigned short* __restrict__ Vb,
                                              unsigned short* __restrict__ Vt) {
  __shared__ unsigned short s[64][72];
  int t = threadIdx.x;
  int bh = blockIdx.y;
  int n0 = blockIdx.x * 64;
  const unsigned short* src = Vb + ((size_t)bh * NSEQ + n0) * DH;
#pragma unroll
  for (int i = 0; i < 2; ++i) {
    int idx = t + i * 256;
    int row = idx >> 3, ch = (idx & 7) * 8;
    *(uint4*)&s[row][ch] = *(const uint4*)(src + (size_t)row * DH + ch);
  }
  __syncthreads();
  unsigned short* dst = Vt + (size_t)bh * DH * NSEQ + n0;
#pragma unroll
  for (int i = 0; i < 2; ++i) {
    int idx = t + i * 256;
    int dh = idx >> 3, ch = (idx & 7) * 8;
    unsigned short tmp[8];
#pragma unroll
    for (int j = 0; j < 8; ++j) tmp[j] = s[ch + j][dh];
    *(uint4*)&dst[(size_t)dh * NSEQ + ch] = *(uint4*)tmp;
  }
}

// ---------------------------------------------------------------------------
// bf16 MFMA GEMM v3: C[M,N] = A[M,K] @ Bt[N,K]^T + bias.
// m97 structure: global_load_lds (16B DMA) into linear LDS, content
// XOR-chunk-swizzled via pre-swizzled global source; 2 barriers per K-step.
// AF32=1 (QKV): A is read DIRECTLY as fp32 (x), staged fp32 in LDS (32KB,
//   16 chunks/row, swizzle XOR row&15), converted to bf16 in the fragment
//   path via v_cvt_pk_bf16_f32 -> the separate cvt_bf16 pass is eliminated.
// AF32=0 (out-proj): A bf16 as before.
// mode 0 (QKV): epilogue via fp32 LDS scratch -> Qb(scaled)/Kb/V0 bf16.
// mode 1: fp32 row-major out. XCD-aware block swizzle.
// ---------------------------------------------------------------------------
template <int TM, int AF32>
__global__ __launch_bounds__(256, AF32 ? 3 : 4) void gemm_bt(
    const unsigned short* __restrict__ Ab, const float* __restrict__ Af,
    const unsigned short* __restrict__ Bt,
    const float* __restrict__ bias, float* __restrict__ outf,
    unsigned short* __restrict__ Qb, unsigned short* __restrict__ Kb,
    unsigned short* __restrict__ V0, int M, int N, int K, int mode) {
  // A region: fp32 TM*64 floats (256B/row) or bf16 TM*64 shorts (128B/row).
  constexpr int ABYTES = AF32 ? TM * 256 : TM * 128;
  __shared__ __align__(16) char Sraw[ABYTES + 128 * 128];
  float* As32 = (float*)Sraw;
  unsigned short* Asb = (unsigned short*)Sraw;
  unsigned short* Bs = (unsigned short*)(Sraw + ABYTES);
  constexpr int MI = TM / 32;
  const int t = threadIdx.x;
  const int wave = t >> 6, lane = t & 63;
  const int ln16 = lane & 15, quad = lane >> 4;
  const int sw = ln16 & 7;

  // XCD-aware swizzle: each XCD gets a contiguous chunk of work ids.
  const int nbx = gridDim.x;
  const int nwg = nbx * gridDim.y;
  int bid = blockIdx.x + blockIdx.y * nbx;
  int nbid = (bid & 7) * (nwg >> 3) + (bid >> 3);  // nwg % 8 == 0 for both gemms
  const int cb = nbid % nbx, rb = nbid / nbx;

  const int rw = (wave >> 1) * (TM / 2);
  const int cw = (wave & 1) * 64;

  // bf16 DMA geometry: one gl16 covers 8 rows x 128B. row8=lane>>3, chunk lane&7.
  // Source chunk pre-swizzled so LDS[row][c] = true[row][c ^ (row&7)].
  const int row8 = lane >> 3;
  const int csw = (lane & 7) ^ row8;
  // fp32 DMA geometry: one gl16 covers 4 rows x 256B. r4=lane>>4, chunk lane&15.
  // LDS[row][c] = true[row][c ^ (row&15)].
  const int r4 = lane >> 4;
  const int c16 = lane & 15;

  f32x4 acc[MI][4];
#pragma unroll
  for (int i = 0; i < MI; ++i)
#pragma unroll
    for (int j = 0; j < 4; ++j) acc[i][j] = (f32x4){0.f, 0.f, 0.f, 0.f};

  const unsigned short* gA =
      AF32 ? nullptr : (Ab + (size_t)(rb * TM + row8) * K + csw * 8);
  const unsigned short* gB = Bt + (size_t)(cb * 128 + row8) * K + csw * 8;

  for (int k0 = 0; k0 < K; k0 += 64) {
    __syncthreads();  // previous tile fully consumed
    if (AF32) {
#pragma unroll
      for (int i = 0; i < TM / 16; ++i) {
        int rt = wave * (TM / 4) + i * 4 + r4;
        int csrc = c16 ^ (rt & 15);
        gl16(Af + (size_t)(rb * TM + rt) * K + k0 + csrc * 4,
             Sraw + (wave * (TM / 4) + i * 4) * 256);
      }
    } else {
#pragma unroll
      for (int i = 0; i < MI; ++i) {
        int rr = wave * (TM / 4) + i * 8;
        gl16(gA + (size_t)rr * K + k0, &Asb[rr * 64]);
      }
    }
#pragma unroll
    for (int i = 0; i < 4; ++i) {
      int rr = wave * 32 + i * 8;
      gl16(gB + (size_t)rr * K + k0, &Bs[rr * 64]);
    }
    asm volatile("s_waitcnt vmcnt(0)" ::: "memory");
    __syncthreads();  // tile visible to all waves

#pragma unroll
    for (int kh = 0; kh < 2; ++kh) {
      bf16x8 a[MI], b[4];
#pragma unroll
      for (int mi = 0; mi < MI; ++mi) {
        int row = rw + mi * 16 + ln16;
        if (AF32) {
          // row & 15 == ln16 (rw, mi*16 are multiples of 16)
          int cf0 = (kh * 8 + quad * 2) ^ ln16;
          int cf1 = (kh * 8 + quad * 2 + 1) ^ ln16;
          f32x4 lo = *(const f32x4*)(As32 + row * 64 + cf0 * 4);
          f32x4 hi = *(const f32x4*)(As32 + row * 64 + cf1 * 4);
          unsigned int u0, u1, u2, u3;
          asm("v_cvt_pk_bf16_f32 %0, %1, %2" : "=v"(u0) : "v"(lo[0]), "v"(lo[1]));
          asm("v_cvt_pk_bf16_f32 %0, %1, %2" : "=v"(u1) : "v"(lo[2]), "v"(lo[3]));
          asm("v_cvt_pk_bf16_f32 %0, %1, %2" : "=v"(u2) : "v"(hi[0]), "v"(hi[1]));
          asm("v_cvt_pk_bf16_f32 %0, %1, %2" : "=v"(u3) : "v"(hi[2]), "v"(hi[3]));
          union { unsigned int u[4]; bf16x8 v; } A8;
          A8.u[0] = u0; A8.u[1] = u1; A8.u[2] = u2; A8.u[3] = u3;
          a[mi] = A8.v;
        } else {
          a[mi] = *(const bf16x8*)&Asb[row * 64 + (((kh << 2) | quad) ^ sw) * 8];
        }
      }
#pragma unroll
      for (int ni = 0; ni < 4; ++ni) {
        int row = cw + ni * 16 + ln16;
        b[ni] = *(const bf16x8*)&Bs[row * 64 + (((kh << 2) | quad) ^ sw) * 8];
      }
#pragma unroll
      for (int mi = 0; mi < MI; ++mi)
#pragma unroll
        for (int ni = 0; ni < 4; ++ni)
          acc[mi][ni] = __builtin_amdgcn_mfma_f32_16x16x32_bf16(a[mi], b[ni],
                                                                acc[mi][ni], 0, 0, 0);
    }
  }

  if (mode == 0) {
    __syncthreads();  // all waves done with LDS tiles; reuse as fp32 C-scratch
    // 768^-0.5 * log2(e): attention uses raw v_exp_f32 (2^x), so the log2e
    // factor is folded into the Q scale here. exp2(S*log2e) == exp(S).
    const float scale = 0.0520587731f;
    int col0abs = cb * 128 + cw;                 // multiple of 64
    int which = (col0abs >= 2 * DIM) ? 2 : ((col0abs >= DIM) ? 1 : 0);
    int h = (col0abs - which * DIM) >> 6;        // wave covers one full head
    unsigned short* dstp = (which == 0) ? Qb : ((which == 1) ? Kb : V0);
    const float mul = (which == 0) ? scale : 1.f;
    float* Cs = (float*)Sraw + wave * (16 * 68);  // 16 rows x 68 floats per wave
    float bvv[4];
#pragma unroll
    for (int ni = 0; ni < 4; ++ni) bvv[ni] = bias[col0abs + ni * 16 + ln16];
#pragma unroll
    for (int mi = 0; mi < MI; ++mi) {
#pragma unroll
      for (int ni = 0; ni < 4; ++ni)
#pragma unroll
        for (int r = 0; r < 4; ++r)
          Cs[(quad * 4 + r) * 68 + ni * 16 + ln16] = (acc[mi][ni][r] + bvv[ni]) * mul;
      __asm__ volatile("s_waitcnt lgkmcnt(0)" ::: "memory");  // wave-local region
      int token = rb * TM + rw + mi * 16 + ln16;
      int bb = token >> 12, nn = token & (NSEQ - 1);
      const float* src = &Cs[ln16 * 68 + quad * 16];
      float4 c0 = *(const float4*)(src + 0);
      float4 c1 = *(const float4*)(src + 4);
      float4 c2 = *(const float4*)(src + 8);
      float4 c3 = *(const float4*)(src + 12);
      unsigned short tmp[16];
      tmp[0] = f2bf(c0.x);  tmp[1] = f2bf(c0.y);  tmp[2] = f2bf(c0.z);  tmp[3] = f2bf(c0.w);
      tmp[4] = f2bf(c1.x);  tmp[5] = f2bf(c1.y);  tmp[6] = f2bf(c1.z);  tmp[7] = f2bf(c1.w);
      tmp[8] = f2bf(c2.x);  tmp[9] = f2bf(c2.y);  tmp[10] = f2bf(c2.z); tmp[11] = f2bf(c2.w);
      tmp[12] = f2bf(c3.x); tmp[13] = f2bf(c3.y); tmp[14] = f2bf(c3.z); tmp[15] = f2bf(c3.w);
      unsigned short* dp =
          dstp + ((size_t)(bb * HEADS + h) * NSEQ + nn) * DH + quad * 16;
      *(uint4*)&dp[0] = *(uint4*)&tmp[0];
      *(uint4*)&dp[8] = *(uint4*)&tmp[8];
      __asm__ volatile("s_waitcnt lgkmcnt(0)" ::: "memory");  // reads done before next mi writes
    }
  } else {
#pragma unroll
    for (int ni = 0; ni < 4; ++ni) {
      int col = cb * 128 + cw + ni * 16 + ln16;
      float bv2 = bias[col];
#pragma unroll
      for (int mi = 0; mi < MI; ++mi)
#pragma unroll
        for (int r = 0; r < 4; ++r) {
          int token = rb * TM + rw + mi * 16 + quad * 4 + r;
          outf[(size_t)token * N + col] = acc[mi][ni][r] + bv2;
        }
    }
  }
}

// ---------------------------------------------------------------------------
// MFMA flash attention v4 (reverted to round-2 code, measured 119.9us):
// swapped QK^T + in-register P exchange (cvt_pk_bf16 + permlane swaps),
// global_load_lds double-buffered staging (1 barrier/tile), register
// ones-fragment denominator, exp2 with log2e folded into Q scale upstream,
// XCD-aware block swizzle (3 heads' K/V per XCD -> fits 4MB L2).
// ---------------------------------------------------------------------------
__global__ __launch_bounds__(256, 3) void attn_mfma4(
    const unsigned short* __restrict__ Qg, const unsigned short* __restrict__ Kg,
    const unsigned short* __restrict__ Vtg, unsigned short* __restrict__ ctxb) {
  __shared__ unsigned short Ks[2][64][64];   // [buf][key][dh], chunk-XOR-swizzled
  __shared__ unsigned short Vts[2][64][64];  // [buf][dh][key], chunk-XOR-swizzled

  const int t = threadIdx.x;
  const int wave = t >> 6, lane = t & 63;
  const int ln16 = lane & 15, quad = lane >> 4;

  // XCD swizzle: nwg = 32*24 = 768, 96 per XCD = 3 heads x 32 q-blocks.
  int bid = blockIdx.x + blockIdx.y * 32;
  int nbid = (bid & 7) * 96 + (bid >> 3);
  const int bh = nbid >> 5;
  const int q0 = (nbid & 31) * 128;

  // Q fragments (registers, whole kernel)
  const unsigned short* Qp = Qg + ((size_t)bh * NSEQ + q0 + wave * 32) * DH;
  bf16x8 qf[2][2];
#pragma unroll
  for (int mi = 0; mi < 2; ++mi)
#pragma unroll
    for (int kh = 0; kh < 2; ++kh)
      qf[mi][kh] = *(const bf16x8*)(Qp + (size_t)(mi * 16 + ln16) * DH + kh * 32 + quad * 8);

  f32x4 O[2][5];
#pragma unroll
  for (int mi = 0; mi < 2; ++mi)
#pragma unroll
    for (int nt = 0; nt < 5; ++nt) O[mi][nt] = (f32x4){0.f, 0.f, 0.f, 0.f};

  const unsigned short* Kbase = Kg + (size_t)bh * NSEQ * DH;
  const unsigned short* Vbase = Vtg + (size_t)bh * DH * NSEQ;

  // staging geometry: per gl16 a wave covers 8 rows x 128B; row = lane>>3,
  // chunk = lane&7. Source chunk pre-swizzled by row&7 so that
  // LDS[row][c] = true[row][c ^ (row&7)] (16B-chunk XOR swizzle).
  const int row8 = lane >> 3;
  const int csw = (lane & 7) ^ row8;

  auto stage = [&](int b, int kk) {
#pragma unroll
    for (int i = 0; i < 2; ++i) {
      int rr = wave * 16 + i * 8;
      gl16(Kbase + (size_t)(kk + rr + row8) * DH + csw * 8, &Ks[b][rr][0]);
      gl16(Vbase + (size_t)(rr + row8) * NSEQ + kk + csw * 8, &Vts[b][rr][0]);
    }
  };

  // ones B-fragment for denominator column (row 0 of B = ones)
  union { unsigned int u[4]; bf16x8 v; } VO;
  {
    unsigned int ow = (ln16 == 0) ? 0x3F803F80u : 0u;
    VO.u[0] = ow; VO.u[1] = ow; VO.u[2] = ow; VO.u[3] = ow;
  }
  const bf16x8 vone = VO.v;

  stage(0, 0);
  const int sw = ln16 & 7;
  int buf = 0;

  for (int k0 = 0; k0 < NSEQ; k0 += 64) {
    asm volatile("s_waitcnt vmcnt(0)" ::: "memory");  // own DMA done
    __syncthreads();                                  // everyone's DMA done; prev tile consumed
    if (k0 + 64 < NSEQ) stage(buf ^ 1, k0 + 64);      // prefetch DMA under this tile's compute

    // S~ = K.Q^T  (swapped operands: col=ln16=query, row=quad*4+r=key)
    f32x4 S[2][4];
    __builtin_amdgcn_s_setprio(1);
#pragma unroll
    for (int nt = 0; nt < 4; ++nt) {
      const unsigned short* kr = &Ks[buf][nt * 16 + ln16][0];
      bf16x8 kb0 = *(const bf16x8*)(kr + (quad ^ sw) * 8);
      bf16x8 kb1 = *(const bf16x8*)(kr + ((quad + 4) ^ sw) * 8);
#pragma unroll
      for (int mi = 0; mi < 2; ++mi) {
        f32x4 s = (f32x4){0.f, 0.f, 0.f, 0.f};
        s = __builtin_amdgcn_mfma_f32_16x16x32_bf16(kb0, qf[mi][0], s, 0, 0, 0);
        s = __builtin_amdgcn_mfma_f32_16x16x32_bf16(kb1, qf[mi][1], s, 0, 0, 0);
        S[mi][nt] = s;
      }
    }
    __builtin_amdgcn_s_setprio(0);

    // P = exp2(S~) -> bf16 pack -> in-register quad exchange -> PV A-frags.
    bf16x8 pa[2][2];
#pragma unroll
    for (int mi = 0; mi < 2; ++mi) {
      unsigned int c[4][2];
#pragma unroll
      for (int nt = 0; nt < 4; ++nt) {
        float e0 = exp2_fast(S[mi][nt][0]);
        float e1 = exp2_fast(S[mi][nt][1]);
        float e2 = exp2_fast(S[mi][nt][2]);
        float e3 = exp2_fast(S[mi][nt][3]);
        asm volatile("v_cvt_pk_bf16_f32 %0, %1, %2" : "=v"(c[nt][0]) : "v"(e0), "v"(e1));
        asm volatile("v_cvt_pk_bf16_f32 %0, %1, %2" : "=v"(c[nt][1]) : "v"(e2), "v"(e3));
      }
#pragma unroll
      for (int kh = 0; kh < 2; ++kh) {
        unsigned int a0 = c[2 * kh][0], a1 = c[2 * kh][1];
        unsigned int a2 = c[2 * kh + 1][0], a3 = c[2 * kh + 1][1];
        asm volatile("v_permlane32_swap_b32 %0, %1" : "+v"(a0), "+v"(a2));
        asm volatile("v_permlane16_swap_b32 %0, %1" : "+v"(a0), "+v"(a2));
        asm volatile("v_permlane32_swap_b32 %0, %1" : "+v"(a1), "+v"(a3));
        asm volatile("v_permlane16_swap_b32 %0, %1" : "+v"(a1), "+v"(a3));
        union { unsigned int u[4]; bf16x8 v; } P;
        P.u[0] = a0; P.u[1] = a1; P.u[2] = a2; P.u[3] = a3;
        pa[mi][kh] = P.v;
      }
    }

    // O += P.V (+ ones column accumulates denominator)
    __builtin_amdgcn_s_setprio(1);
#pragma unroll
    for (int nt = 0; nt < 5; ++nt) {
      bf16x8 vb0, vb1;
      if (nt < 4) {
        const unsigned short* vr = &Vts[buf][nt * 16 + ln16][0];
        vb0 = *(const bf16x8*)(vr + (quad ^ sw) * 8);
        vb1 = *(const bf16x8*)(vr + ((quad + 4) ^ sw) * 8);
      } else {
        vb0 = vone; vb1 = vone;
      }
#pragma unroll
      for (int mi = 0; mi < 2; ++mi) {
        O[mi][nt] = __builtin_amdgcn_mfma_f32_16x16x32_bf16(pa[mi][0], vb0, O[mi][nt], 0, 0, 0);
        O[mi][nt] = __builtin_amdgcn_mfma_f32_16x16x32_bf16(pa[mi][1], vb1, O[mi][nt], 0, 0, 0);
      }
    }
    __builtin_amdgcn_s_setprio(0);
    buf ^= 1;
  }

  int bb = bh / HEADS, h = bh % HEADS;
#pragma unroll
  for (int mi = 0; mi < 2; ++mi)
#pragma unroll
    for (int r = 0; r < 4; ++r) {
      float lsum = O[mi][4][r];
      lsum = __shfl(lsum, lane & 48);  // broadcast from ln16==0 of this quad
      float inv = 1.f / lsum;
      int token = q0 + wave * 32 + mi * 16 + quad * 4 + r;
      unsigned short* op = ctxb + ((size_t)(bb * NSEQ + token)) * DIM + h * DH;
#pragma unroll
      for (int nt = 0; nt < 4; ++nt)
        op[nt * 16 + ln16] = f2bf(O[mi][nt][r] * inv);
    }
}

// ---------------------------------------------------------------------------
extern "C" void kernel_launch(void* const* d_in, const int* in_sizes, int n_in,
                              void* d_out, int out_size, void* d_ws, size_t ws_size,
                              hipStream_t stream) {
  const float* x = (const float*)d_in[0];
  const float* w_qkv = (const float*)d_in[1];
  const float* b_qkv = (const float*)d_in[2];
  const float* w_out = (const float*)d_in[3];
  const float* b_out = (const float*)d_in[4];
  float* out = (float*)d_out;

  const size_t plane = (size_t)BH * NSEQ * DH;  // 6,291,456
  unsigned short* wqkvT = (unsigned short*)d_ws;         // [2304][768]
  unsigned short* woutT = wqkvT + (size_t)3 * DIM * DIM; // [768][768]
  unsigned short* Qb = woutT + (size_t)DIM * DIM;        // [bh][n][64]
  unsigned short* Kb = Qb + plane;                       // [bh][n][64]
  unsigned short* V0 = Kb + plane;                       // [bh][n][64]
  unsigned short* Vtb = V0 + plane;                      // [bh][64][n]
  unsigned short* ctxb = Vtb + plane;                    // [8192][768]

  transpose_cvt<<<dim3(3 * DIM / 32, DIM / 32), 256, 0, stream>>>(w_qkv, wqkvT, DIM, 3 * DIM);
  transpose_cvt<<<dim3(DIM / 32, DIM / 32), 256, 0, stream>>>(w_out, woutT, DIM, DIM);

  // QKV GEMM reads x directly as fp32 (cvt pass fused away).
  gemm_bt<128, 1><<<dim3(3 * DIM / 128, BATCH * NSEQ / 128), 256, 0, stream>>>(
      nullptr, x, wqkvT, b_qkv, nullptr, Qb, Kb, V0, BATCH * NSEQ, 3 * DIM, DIM, 0);

  vtrans<<<dim3(NSEQ / 64, BH), 256, 0, stream>>>(V0, Vtb);

  attn_mfma4<<<dim3(NSEQ / 128, BH), 256, 0, stream>>>(Qb, Kb, Vtb, ctxb);

  gemm_bt<64, 0><<<dim3(DIM / 128, BATCH * NSEQ / 64), 256, 0, stream>>>(
      ctxb, nullptr, woutT, b_out, out, nullptr, nullptr, nullptr, BATCH * NSEQ, DIM, DIM, 1);
}